// Round 11
// baseline (906.753 us; speedup 1.0000x reference)
//
#include <hip/hip_runtime.h>

#define IN_F 4096
#define OUT_F 16384
#define MTOK 8192   // B*S

#define BM 256
#define BN 256
#define BK 64
#define NKT (IN_F / BK)   // 64 K-tiles

typedef __attribute__((ext_vector_type(4)))  int   i32x4;
typedef __attribute__((ext_vector_type(4)))  float f32x4;

__device__ __forceinline__ void gload_lds16(const void* g, void* l) {
    __builtin_amdgcn_global_load_lds(
        (const __attribute__((address_space(1))) void*)g,
        (__attribute__((address_space(3))) void*)l,
        16, 0, 0);
}

// ---------------------------------------------------------------------------
// Kernel 1: per-token absmax -> int8 quantize x, store scale
// ---------------------------------------------------------------------------
__global__ __launch_bounds__(256) void k_quant(const float* __restrict__ x,
                                               char* __restrict__ xq,
                                               float* __restrict__ xs) {
    const int m = blockIdx.x;
    const int t = threadIdx.x;
    const float* xrow = x + (size_t)m * IN_F;

    f32x4 v[4];
    float mx = 0.f;
#pragma unroll
    for (int i = 0; i < 4; ++i) {
        v[i] = *(const f32x4*)&xrow[(i * 256 + t) * 4];
        mx = fmaxf(mx, fmaxf(fmaxf(fabsf(v[i].x), fabsf(v[i].y)),
                             fmaxf(fabsf(v[i].z), fabsf(v[i].w))));
    }
#pragma unroll
    for (int off = 32; off > 0; off >>= 1)
        mx = fmaxf(mx, __shfl_xor(mx, off));

    __shared__ float wmax[4];
    const int wid = t >> 6;
    if ((t & 63) == 0) wmax[wid] = mx;
    __syncthreads();
    const float scale = fmaxf(fmaxf(fmaxf(wmax[0], wmax[1]),
                                    fmaxf(wmax[2], wmax[3])), 1e-5f);
    const float inv = 127.0f / scale;

    int* xqi = (int*)(xq + (size_t)m * IN_F);
#pragma unroll
    for (int i = 0; i < 4; ++i) {
        int q0 = (int)rintf(fminf(fmaxf(v[i].x * inv, -128.f), 127.f));
        int q1 = (int)rintf(fminf(fmaxf(v[i].y * inv, -128.f), 127.f));
        int q2 = (int)rintf(fminf(fmaxf(v[i].z * inv, -128.f), 127.f));
        int q3 = (int)rintf(fminf(fmaxf(v[i].w * inv, -128.f), 127.f));
        xqi[i * 256 + t] = (q0 & 255) | ((q1 & 255) << 8) |
                           ((q2 & 255) << 16) | (q3 << 24);
    }
    if (t == 0) xs[m] = scale;
}

// ---------------------------------------------------------------------------
// Kernel 2: ternary int32 weights -> int8 pack
// ---------------------------------------------------------------------------
__global__ __launch_bounds__(256) void k_wconv(const int* __restrict__ wt,
                                               int* __restrict__ w8) {
    const int total4 = OUT_F * IN_F / 4;
    int idx = blockIdx.x * 256 + threadIdx.x;
    const int stride = gridDim.x * 256;
    for (; idx < total4; idx += stride) {
        i32x4 w = *(const i32x4*)&wt[(size_t)idx * 4];
        w8[idx] = (w.x & 255) | ((w.y & 255) << 8) |
                  ((w.z & 255) << 16) | (w.w << 24);
    }
}

// ---------------------------------------------------------------------------
// Kernel 3: i8 GEMM — B DIRECT-TO-REGISTER (L2-served), A-only LDS.
//
// Rationale (R10 post-mortem): with A+B both LDS-staged, LDS traffic/K-tile
// (~1000 cyc/CU) nearly matches the MFMA floor (1306 cyc) and operand-gating
// serializes them; register prefetch of both operands needs +48 VGPR -> over
// the 256 (2 waves/SIMD) budget. Dropping B from LDS cuts LDS to 80 KB/K-tile
// (625 cyc << 1306) and B double-buffers in regs for only +16 VGPR.
// B fragment layout: lane reads Bq[(n0 + lane&15)*4096 + kt*64 + (lane>>4)*16]
// — identical to the MFMA B operand (R1-verified), 16x64B segments per load.
//
// A side (all R10-proven): 3-buffer rotation at x*16384, 64B rows,
// phys chunk = logical ^ ((row>>1)&3) (0 conflicts measured), staging
// permutes global source within each row's 64B, frag read row = lane&15,
// phys chunk = (lane>>4) ^ ((lane>>1)&3).
//
// Per-body issue order: [4x b(kt+1) global] [8x a ds_read] [2x A-stage(kt+2)]
// vmcnt FIFO: at body end, outstanding = stage(kt+1):2 | b(kt+1):4 |
// stage(kt+2):2  -> VM6 retires exactly stage(kt+1) (next body's buffer).
// Prologue: [s0:2 s1:2 b0:4] -> VM6 retires s0. Tail: body62 VM4 (retires
// s63; b63 stays), body63 no wait. Compiler auto-gates b-reg use (vmcnt(8))
// and a-reg use (counted lgkmcnt) — all loads are compiler-visible.
// bA/bB explicit double-buffer via 2-body unroll (rule #20: no runtime idx).
// ---------------------------------------------------------------------------
__global__ __launch_bounds__(512, 2) void k_gemm(
    const char*  __restrict__ Aq,     // [MTOK][IN_F] int8
    const char*  __restrict__ Bq,     // [OUT_F][IN_F] int8
    const float* __restrict__ xs,     // [MTOK]
    const float* __restrict__ wsp,    // [1]
    float*       __restrict__ C) {    // [MTOK][OUT_F]
    __shared__ __align__(16) char lds[49152];   // A only: 3 x 16 KB

    const int t    = threadIdx.x;
    const int lane = t & 63;
    const int wid  = t >> 6;
    const int wr   = wid >> 2;        // 0..1  (M half, 128 rows)
    const int wc   = wid & 3;         // 0..3  (N quarter, 64 cols)

    // XCD band mapping: grid 2048 = 32(M) x 64(N); XCD (bid&7) owns an
    // 8-wide bn band. Bijective.
    const int bid = blockIdx.x;
    const int bn  = (bid & 7) * 8 + ((bid >> 3) & 7);
    const int bm  = bid >> 6;
    const int mBase = bm * BM;
    const int nBase = bn * BN;

    // --- A staging source (R10-proven): thread t -> row t>>2, phys chunk
    // t&3, logical chunk (t&3)^((t>>3)&3). Second load: row+128.
    const int r0 = t >> 2;
    const int c0 = (((t & 3) ^ ((t >> 3) & 3)) << 4);

#define STAGE(kt, bx) do {                                                     \
        const size_t ks = (size_t)(kt) * BK;                                   \
        gload_lds16(Aq + (size_t)(mBase + r0) * IN_F + ks + c0,                \
                    lds + (bx) * 16384 + wid * 1024);                          \
        gload_lds16(Aq + (size_t)(mBase + 128 + r0) * IN_F + ks + c0,          \
                    lds + (bx) * 16384 + 8192 + wid * 1024);                   \
    } while (0)

    // --- A fragment read (R10-proven): row = lane&15,
    // phys chunk = (lane>>4) ^ ((row>>1)&3)
    const int fOff = (lane & 15) * 64 + ((((lane >> 4) ^ (lane >> 1)) & 3) << 4);
    const char* ldsA = lds + wr * 8192;            // + x*16384 + mi*1024

    // --- B direct-load base: lane covers row nBase+wc*64+ni*16+(lane&15),
    // 16B chunk (lane>>4) at column kt*64. ni stride = 16*IN_F = 65536 B.
    const char* bBase = Bq + (size_t)(nBase + wc * 64 + (lane & 15)) * IN_F
                           + ((lane >> 4) << 4);

#define LOADB(dst, kt)                                                         \
    _Pragma("unroll")                                                          \
    for (int ni = 0; ni < 4; ++ni)                                             \
        dst[ni] = *(const i32x4*)(bBase + ni * 65536 + (size_t)(kt) * BK);

#define RDA(a, XO)                                                             \
    _Pragma("unroll")                                                          \
    for (int mi = 0; mi < 8; ++mi)                                             \
        a[mi] = *(const i32x4*)(ldsA + (XO) + mi * 1024 + fOff);

#define MFMAC(a, b)                                                            \
    __builtin_amdgcn_s_setprio(1);                                             \
    _Pragma("unroll")                                                          \
    for (int mi = 0; mi < 8; ++mi)                                             \
        _Pragma("unroll")                                                      \
        for (int ni = 0; ni < 4; ++ni)                                         \
            acc[mi][ni] = __builtin_amdgcn_mfma_i32_16x16x64_i8(               \
                a[mi], b[ni], acc[mi][ni], 0, 0, 0);                           \
    __builtin_amdgcn_s_setprio(0);

#define BAR()   __builtin_amdgcn_s_barrier()
#define VM6()   asm volatile("s_waitcnt vmcnt(6)" ::: "memory")
#define VM4()   asm volatile("s_waitcnt vmcnt(4)" ::: "memory")

    i32x4 acc[8][4];
#pragma unroll
    for (int i = 0; i < 8; ++i)
#pragma unroll
        for (int j = 0; j < 4; ++j)
            acc[i][j] = (i32x4){0, 0, 0, 0};

    i32x4 bA[4], bB[4];

    // ---- prologue: FIFO [s0:2, s1:2, b0:4]; VM6 retires s0 exactly
    STAGE(0, 0);
    STAGE(1, 1);
    LOADB(bA, 0);
    VM6();
    BAR();

    // ---- steady state: bodies 0..61 (31 iters x 2), all stages/loads live
    int x = 0, x2 = 2;   // kt%3, (kt+2)%3
#define GBODY(kt, BU, BL) do {                                                 \
        LOADB(BL, (kt) + 1);                                                   \
        i32x4 a[8];                                                            \
        RDA(a, x * 16384);                                                     \
        STAGE((kt) + 2, x2);                                                   \
        MFMAC(a, BU);                                                          \
        VM6();                                                                 \
        BAR();                                                                 \
        x  = (x  == 2) ? 0 : x  + 1;                                           \
        x2 = (x2 == 2) ? 0 : x2 + 1;                                           \
    } while (0)

    for (int it = 0; it < 31; ++it) {
        const int k0 = 2 * it;
        GBODY(k0,     bA, bB);
        GBODY(k0 + 1, bB, bA);
    }

    // ---- body 62: load b(63), no stage; VM4 retires s63 (b63 in flight)
    {
        LOADB(bB, 63);
        i32x4 a[8];
        RDA(a, x * 16384);               // x = 62%3 = 2
        MFMAC(a, bA);
        VM4();
        BAR();
    }
    // ---- body 63: buf 0; compiler gates bB via vmcnt
    {
        i32x4 a[8];
        RDA(a, 0);                       // 63%3 = 0
        MFMAC(a, bB);
    }

    // ---- epilogue: D row = (lane>>4)*4 + r, col = lane&15 (verified R1-R10)
    const float wsc = wsp[0] * (1.0f / 127.0f);
#pragma unroll
    for (int mi = 0; mi < 8; ++mi) {
        float rs[4];
#pragma unroll
        for (int r = 0; r < 4; ++r)
            rs[r] = xs[mBase + wr * 128 + mi * 16 + (lane >> 4) * 4 + r] * wsc;
#pragma unroll
        for (int ni = 0; ni < 4; ++ni) {
            const int col = nBase + wc * 64 + ni * 16 + (lane & 15);
#pragma unroll
            for (int r = 0; r < 4; ++r) {
                const int row = mBase + wr * 128 + mi * 16 + (lane >> 4) * 4 + r;
                C[(size_t)row * OUT_F + col] = (float)acc[mi][ni][r] * rs[r];
            }
        }
    }
}

// ---------------------------------------------------------------------------
extern "C" void kernel_launch(void* const* d_in, const int* in_sizes, int n_in,
                              void* d_out, int out_size, void* d_ws, size_t ws_size,
                              hipStream_t stream) {
    const float* x   = (const float*)d_in[0];
    const int*   wt  = (const int*)d_in[1];
    const float* wsp = (const float*)d_in[2];
    float* out = (float*)d_out;

    char*  w8 = (char*)d_ws;
    char*  xq = (char*)d_ws + (size_t)OUT_F * IN_F;
    float* xs = (float*)((char*)d_ws + (size_t)OUT_F * IN_F
                                     + (size_t)MTOK * IN_F);

    k_wconv<<<8192, 256, 0, stream>>>(wt, (int*)w8);
    k_quant<<<MTOK, 256, 0, stream>>>(x, xq, xs);

    const int grid = (MTOK / BM) * (OUT_F / BN);  // 32 * 64 = 2048
    k_gemm<<<grid, 512, 0, stream>>>(xq, w8, xs, wsp, out);
}

// Round 12
// 570.917 us; speedup vs baseline: 1.5882x; 1.5882x over previous
//
#include <hip/hip_runtime.h>

#define IN_F 4096
#define OUT_F 16384
#define MTOK 8192   // B*S

#define BM 256
#define BN 256
#define BKB 128                 // K-bytes (=elements, i8) per K-tile
#define NKT (IN_F / BKB)        // 32 K-tiles
#define NIT (NKT / 2)           // 16 iterations, 2 K-tiles each

typedef __attribute__((ext_vector_type(4)))  int   i32x4;
typedef __attribute__((ext_vector_type(4)))  float f32x4;

__device__ __forceinline__ void gload_lds16(const void* g, void* l) {
    __builtin_amdgcn_global_load_lds(
        (const __attribute__((address_space(1))) void*)g,
        (__attribute__((address_space(3))) void*)l,
        16, 0, 0);
}

// ---------------------------------------------------------------------------
// Kernel 1: per-token absmax -> int8 quantize x, store scale
// ---------------------------------------------------------------------------
__global__ __launch_bounds__(256) void k_quant(const float* __restrict__ x,
                                               char* __restrict__ xq,
                                               float* __restrict__ xs) {
    const int m = blockIdx.x;
    const int t = threadIdx.x;
    const float* xrow = x + (size_t)m * IN_F;

    f32x4 v[4];
    float mx = 0.f;
#pragma unroll
    for (int i = 0; i < 4; ++i) {
        v[i] = *(const f32x4*)&xrow[(i * 256 + t) * 4];
        mx = fmaxf(mx, fmaxf(fmaxf(fabsf(v[i].x), fabsf(v[i].y)),
                             fmaxf(fabsf(v[i].z), fabsf(v[i].w))));
    }
#pragma unroll
    for (int off = 32; off > 0; off >>= 1)
        mx = fmaxf(mx, __shfl_xor(mx, off));

    __shared__ float wmax[4];
    const int wid = t >> 6;
    if ((t & 63) == 0) wmax[wid] = mx;
    __syncthreads();
    const float scale = fmaxf(fmaxf(fmaxf(wmax[0], wmax[1]),
                                    fmaxf(wmax[2], wmax[3])), 1e-5f);
    const float inv = 127.0f / scale;

    int* xqi = (int*)(xq + (size_t)m * IN_F);
#pragma unroll
    for (int i = 0; i < 4; ++i) {
        int q0 = (int)rintf(fminf(fmaxf(v[i].x * inv, -128.f), 127.f));
        int q1 = (int)rintf(fminf(fmaxf(v[i].y * inv, -128.f), 127.f));
        int q2 = (int)rintf(fminf(fmaxf(v[i].z * inv, -128.f), 127.f));
        int q3 = (int)rintf(fminf(fmaxf(v[i].w * inv, -128.f), 127.f));
        xqi[i * 256 + t] = (q0 & 255) | ((q1 & 255) << 8) |
                           ((q2 & 255) << 16) | (q3 << 24);
    }
    if (t == 0) xs[m] = scale;
}

// ---------------------------------------------------------------------------
// Kernel 2: ternary int32 weights -> int8 pack
// ---------------------------------------------------------------------------
__global__ __launch_bounds__(256) void k_wconv(const int* __restrict__ wt,
                                               int* __restrict__ w8) {
    const int total4 = OUT_F * IN_F / 4;
    int idx = blockIdx.x * 256 + threadIdx.x;
    const int stride = gridDim.x * 256;
    for (; idx < total4; idx += stride) {
        i32x4 w = *(const i32x4*)&wt[(size_t)idx * 4];
        w8[idx] = (w.x & 255) | ((w.y & 255) << 8) |
                  ((w.z & 255) << 16) | (w.w << 24);
    }
}

// ---------------------------------------------------------------------------
// Kernel 3: i8 GEMM — R4 (503us) with the NON-LOAD-BEARING BARRIERS REMOVED.
//
// R4 had 16 barriers/iter: a BAR+lgkmcnt(0) before every MFMA cluster
// (lockstep role-split) plus end-phase BARs. Hazard audit: correctness only
// needs (a) a barrier between the last READ of a region and a STAGE into it
// [ph2end for B0, ph3end for A0/B1, ph7end/ph8end for next ph1's A1], and
// (b) VM6+BAR before reading a freshly staged tile [ph4end, ph8end].
// Per-wave read->MFMA ordering is compiler-enforced via counted lgkmcnt
// (plain C++ ds_reads, no inline-asm lgkm -> rule #18 safe).
// => 6 barriers/iter, and waves can SLIP phase-to-phase: one wave's ds_reads
// now run under another wave's MFMA cluster (convoy broken, 0 extra VGPR).
//
// Geometry/swizzle/ledger identical to R4 (all measured: 0 conflicts):
// 256x256 tile, BK=128, 8 waves (2Mx4N, wave 128x64).
// LDS 128KB: A[2buf][2half][128rows][128B], B same (+64KB).
// phys chunk = logical ^ (row&7); staging permutes global SOURCE within
// each row's 128B. Frag read: row=lane&15, chunk=(kk*4+(lane>>4))^(lane&7).
// Stage order ph1:A1(2t+1) ph3:B0(2t+2) ph4:B1,A0(2t+2) ph5:A1(2t+2)
// ph6:B0(2t+3) ph7:B1(2t+3) ph8:A0(2t+3). FIFO: VM6@ph4 retires exactly
// tile 2t+1 (read ph5-8); VM6@ph8 exactly 2t+2. Last iter: VM0.
// ---------------------------------------------------------------------------
__global__ __launch_bounds__(512, 2) void k_gemm(
    const char*  __restrict__ Aq,     // [MTOK][IN_F] int8
    const char*  __restrict__ Bq,     // [OUT_F][IN_F] int8
    const float* __restrict__ xs,     // [MTOK]
    const float* __restrict__ wsp,    // [1]
    float*       __restrict__ C) {    // [MTOK][OUT_F]
    __shared__ __align__(16) char lds[131072];   // A: 0..64K, B: 64K..128K

    const int t    = threadIdx.x;
    const int lane = t & 63;
    const int wid  = t >> 6;
    const int wr   = wid >> 2;        // 0..1  (M half)
    const int wc   = wid & 3;         // 0..3  (N quarter)

    // XCD band mapping: grid 2048 = 32(M) x 64(N); XCD (bid&7) owns an
    // 8-wide bn band. Bijective.
    const int bid = blockIdx.x;
    const int bn  = (bid & 7) * 8 + ((bid >> 3) & 7);
    const int bm  = bid >> 6;
    const int mBase = bm * BM;
    const int nBase = bn * BN;

    // --- staging source: phys chunk pc = j*512+t; row = pc>>3,
    // src col-chunk = ((pc&7) ^ (row&7)) * 16
    const int r0 = t >> 3;
    const int c0 = ((t ^ r0) & 7) * 16;

#define STAGE_A(h, b, kt) do {                                                 \
        const size_t _s = (size_t)(mBase + (h) * 128 + r0) * IN_F + c0         \
                        + (size_t)(kt) * BKB;                                  \
        char* _d = lds + (b) * 32768 + (h) * 16384 + wid * 1024;               \
        gload_lds16(Aq + _s, _d);                                              \
        gload_lds16(Aq + _s + (size_t)64 * IN_F, _d + 8192);                   \
    } while (0)
#define STAGE_B(h, b, kt) do {                                                 \
        const size_t _s = (size_t)(nBase + (h) * 128 + r0) * IN_F + c0         \
                        + (size_t)(kt) * BKB;                                  \
        char* _d = lds + 65536 + (b) * 32768 + (h) * 16384 + wid * 1024;       \
        gload_lds16(Bq + _s, _d);                                              \
        gload_lds16(Bq + _s + (size_t)64 * IN_F, _d + 8192);                   \
    } while (0)

    // --- fragment read offsets: row = lane&15, chunk = (kk*4+(lane>>4))^(lane&7)
    int fOff[2];
#pragma unroll
    for (int kk = 0; kk < 2; ++kk)
        fOff[kk] = (lane & 15) * 128 + (((kk * 4 + (lane >> 4)) ^ (lane & 7)) << 4);
    const char* ldsA = lds + wr * 16384;                    // + buf*32768 + mi*2048
    const char* ldsB = lds + 65536 + (wc >> 1) * 16384;     // + buf*32768 + ni*2048
    const int bNi = (wc & 1) * 4;   // wave's ni sub-offset within its B half

#define RD_A(dst, bOfs, miB)                                                   \
    _Pragma("unroll")                                                          \
    for (int mi = 0; mi < 4; ++mi)                                             \
        _Pragma("unroll")                                                      \
        for (int kk = 0; kk < 2; ++kk)                                         \
            dst[mi][kk] = *(const i32x4*)(ldsA + (bOfs) +                      \
                              ((miB) + mi) * 2048 + fOff[kk]);
#define RD_B(dst, bOfs, niB)                                                   \
    _Pragma("unroll")                                                          \
    for (int ni = 0; ni < 2; ++ni)                                             \
        _Pragma("unroll")                                                      \
        for (int kk = 0; kk < 2; ++kk)                                         \
            dst[ni][kk] = *(const i32x4*)(ldsB + (bOfs) +                      \
                              (bNi + (niB) + ni) * 2048 + fOff[kk]);
#define MFMA_Q(Af, MIB, Bf, NIB)                                               \
    __builtin_amdgcn_s_setprio(1);                                             \
    _Pragma("unroll")                                                          \
    for (int mi = 0; mi < 4; ++mi)                                             \
        _Pragma("unroll")                                                      \
        for (int ni = 0; ni < 2; ++ni)                                         \
            _Pragma("unroll")                                                  \
            for (int kk = 0; kk < 2; ++kk)                                     \
                acc[(MIB) + mi][(NIB) + ni] =                                  \
                    __builtin_amdgcn_mfma_i32_16x16x64_i8(                     \
                        Af[mi][kk], Bf[ni][kk], acc[(MIB) + mi][(NIB) + ni],   \
                        0, 0, 0);                                              \
    __builtin_amdgcn_s_setprio(0);
#define BAR()   __builtin_amdgcn_s_barrier()
#define VM6()   asm volatile("s_waitcnt vmcnt(6)" ::: "memory")
#define VM0()   asm volatile("s_waitcnt vmcnt(0)" ::: "memory")

    i32x4 acc[8][4];
#pragma unroll
    for (int i = 0; i < 8; ++i)
#pragma unroll
        for (int j = 0; j < 4; ++j)
            acc[i][j] = (i32x4){0, 0, 0, 0};

    i32x4 aLo[4][2], aHi[4][2], bLo[2][2], bHi[2][2];

    // ---- prologue: tile0 fully (8 loads) + tile1 {B0,B1,A0} (6 loads)
    STAGE_A(0, 0, 0); STAGE_A(1, 0, 0); STAGE_B(0, 0, 0); STAGE_B(1, 0, 0);
    STAGE_B(0, 1, 1); STAGE_B(1, 1, 1); STAGE_A(0, 1, 1);
    VM6();           // tile0's 8 retired; tile1's 6 in flight
    BAR();

    for (int it = 0; it < NIT; ++it) {
        const int kt1 = 2 * it + 1;
        const int kn0 = 2 * it + 2;
        const int kn1 = 2 * it + 3;
        const bool more = (it < NIT - 1);

        // ---- ph1 (no barrier: reads+MFMA flow; slip allowed)
        RD_A(aLo, 0, 0); RD_B(bLo, 0, 0);
        STAGE_A(1, 1, kt1);
        MFMA_Q(aLo, 0, bLo, 0);
        // ---- ph2 (BAR: all B reads of buf0 done -> ph3 may stage B0)
        RD_B(bHi, 0, 2);
        MFMA_Q(aLo, 0, bHi, 2);
        BAR();
        // ---- ph3 (BAR: all A reads of buf0 done -> ph4 may stage A0/B1)
        RD_A(aHi, 0, 4);
        if (more) STAGE_B(0, 0, kn0);
        MFMA_Q(aHi, 4, bHi, 2);
        BAR();
        // ---- ph4 (VM6+BAR: tile 2t+1 fully landed -> ph5 may read buf1)
        if (more) { STAGE_B(1, 0, kn0); STAGE_A(0, 0, kn0); }
        MFMA_Q(aHi, 4, bLo, 0);
        if (more) { VM6(); } else { VM0(); }
        BAR();
        // ---- ph5 (no barrier)
        RD_A(aLo, 32768, 0); RD_B(bLo, 32768, 0);
        if (more) STAGE_A(1, 0, kn0);
        MFMA_Q(aLo, 0, bLo, 0);
        // ---- ph6 (BAR: B reads of buf1 done -> ph7 may stage B1(kn1))
        RD_B(bHi, 32768, 2);
        MFMA_Q(aLo, 0, bHi, 2);
        BAR();
        // ---- ph7 (BAR: A reads of buf1 done -> ph8 A0 / next ph1 A1 stage)
        RD_A(aHi, 32768, 4);
        if (more) STAGE_B(1, 1, kn1);
        MFMA_Q(aHi, 4, bHi, 2);
        BAR();
        // ---- ph8 (VM6+BAR: tile 2t+2 fully landed -> next ph1 reads buf0)
        if (more) { STAGE_B(0, 1, kn1); STAGE_A(0, 1, kn1); }
        MFMA_Q(aHi, 4, bLo, 0);
        if (more) { VM6(); } else { VM0(); }
        BAR();
    }

    // ---- epilogue: D row = (lane>>4)*4 + r, col = lane&15 (verified R1-R11)
    const float wsc = wsp[0] * (1.0f / 127.0f);
#pragma unroll
    for (int mi = 0; mi < 8; ++mi) {
        float rs[4];
#pragma unroll
        for (int r = 0; r < 4; ++r)
            rs[r] = xs[mBase + wr * 128 + mi * 16 + (lane >> 4) * 4 + r] * wsc;
#pragma unroll
        for (int ni = 0; ni < 4; ++ni) {
            const int col = nBase + wc * 64 + ni * 16 + (lane & 15);
#pragma unroll
            for (int r = 0; r < 4; ++r) {
                const int row = mBase + wr * 128 + mi * 16 + (lane >> 4) * 4 + r;
                C[(size_t)row * OUT_F + col] = (float)acc[mi][ni][r] * rs[r];
            }
        }
    }
}

// ---------------------------------------------------------------------------
extern "C" void kernel_launch(void* const* d_in, const int* in_sizes, int n_in,
                              void* d_out, int out_size, void* d_ws, size_t ws_size,
                              hipStream_t stream) {
    const float* x   = (const float*)d_in[0];
    const int*   wt  = (const int*)d_in[1];
    const float* wsp = (const float*)d_in[2];
    float* out = (float*)d_out;

    char*  w8 = (char*)d_ws;
    char*  xq = (char*)d_ws + (size_t)OUT_F * IN_F;
    float* xs = (float*)((char*)d_ws + (size_t)OUT_F * IN_F
                                     + (size_t)MTOK * IN_F);

    k_wconv<<<8192, 256, 0, stream>>>(wt, (int*)w8);
    k_quant<<<MTOK, 256, 0, stream>>>(x, xq, xs);

    const int grid = (MTOK / BM) * (OUT_F / BN);  // 32 * 64 = 2048
    k_gemm<<<grid, 512, 0, stream>>>(xq, w8, xs, wsp, out);
}